// Round 7
// baseline (245.037 us; speedup 1.0000x reference)
//
#include <hip/hip_runtime.h>
#include <cstdint>

typedef unsigned short u16;
typedef __bf16 bf16x8 __attribute__((ext_vector_type(8)));
typedef short s16x4 __attribute__((ext_vector_type(4)));
typedef int s32x2 __attribute__((ext_vector_type(2)));
typedef float f32x4 __attribute__((ext_vector_type(4)));

// ---- bf16 helpers (RTNE, matching XLA/ml_dtypes) ----
__device__ __forceinline__ u16 f2bf(float f) {
    unsigned u = __float_as_uint(f);
    u = (u + 0x7fffu + ((u >> 16) & 1u)) >> 16;
    return (u16)u;
}
__device__ __forceinline__ float bf2f(u16 h) {
    return __uint_as_float(((unsigned)h) << 16);
}

// async global->LDS, 16B per lane; LDS dest = wave-uniform base + lane*16
__device__ __forceinline__ void glds16(const u16* g, u16* l) {
    __builtin_amdgcn_global_load_lds(
        (const __attribute__((address_space(1))) void*)g,
        (__attribute__((address_space(3))) void*)l, 16, 0, 0);
}

// pack 4 positive floats -> 4 bf16 (round-half-up; ties-only diff vs RTNE)
__device__ __forceinline__ s16x4 pack_bf4(float p0, float p1, float p2, float p3) {
    unsigned a0 = __float_as_uint(p0) + 0x8000u;
    unsigned a1 = __float_as_uint(p1) + 0x8000u;
    unsigned a2 = __float_as_uint(p2) + 0x8000u;
    unsigned a3 = __float_as_uint(p3) + 0x8000u;
    s32x2 pk = {(int)__builtin_amdgcn_perm(a1, a0, 0x07060302u),
                (int)__builtin_amdgcn_perm(a3, a2, 0x07060302u)};
    return __builtin_bit_cast(s16x4, pk);
}

#if __has_builtin(__builtin_amdgcn_mfma_f32_16x16x16bf16_1k)
#define MFMA16(a, b, c) __builtin_amdgcn_mfma_f32_16x16x16bf16_1k(a, b, c, 0, 0, 0)
#else
static __device__ __forceinline__ f32x4 mfma16_asm(s16x4 a, s16x4 b, f32x4 c) {
    asm("v_mfma_f32_16x16x16_bf16 %0, %1, %2, %0" : "+v"(c) : "v"(a), "v"(b));
    return c;
}
#define MFMA16(a, b, c) mfma16_asm(a, b, c)
#endif

// ============================================================================
// 1. prep: ternary-quantize both weights (8 elems/lane) + cast x to bf16.
//    GRID = 1280 quant + 2048 cast = 3328.
// ============================================================================
__global__ __launch_bounds__(256) void prep(
    const float* __restrict__ w_qkv, const float* __restrict__ w_proj,
    const float* __restrict__ x,
    u16* __restrict__ wqkv_b, u16* __restrict__ wproj_b, u16* __restrict__ xb) {
    int bid = blockIdx.x;
    if (bid < 1280) {
        const float* w; u16* o; size_t base;
        if (bid < 768) { w = w_qkv; o = wqkv_b; base = (size_t)bid * 2048; }
        else { w = w_proj; o = wproj_b; base = (size_t)(bid - 768) * 2048; }
        size_t i = base + (size_t)threadIdx.x * 8;
        float4 A = *(const float4*)(w + i);
        float4 B = *(const float4*)(w + i + 4);
        float wf[8] = {A.x, A.y, A.z, A.w, B.x, B.y, B.z, B.w};
        float wbf[8], ab[8];
        #pragma unroll
        for (int e = 0; e < 8; ++e) { wbf[e] = bf2f(f2bf(wf[e])); ab[e] = fabsf(wbf[e]); }
        float s = ((ab[0] + ab[1]) + (ab[2] + ab[3])) + ((ab[4] + ab[5]) + (ab[6] + ab[7]));
        s += __shfl_xor(s, 1);
        s += __shfl_xor(s, 2);
        s += __shfl_xor(s, 4);   // 8-lane cluster = one 64-elem group
        float scale = bf2f(f2bf(s * (1.0f / 64.0f)));
        if (scale < 1e-8f) scale = 1e-8f;
        u16 ov[8];
        #pragma unroll
        for (int e = 0; e < 8; ++e) {
            float t = bf2f(f2bf(wbf[e] / scale));
            float q = rintf(t);
            q = fminf(1.0f, fmaxf(-1.0f, q));
            float d = bf2f(f2bf(q * scale - wbf[e]));
            ov[e] = f2bf(wbf[e] + d);
        }
        *(int4*)(o + i) = *(const int4*)ov;
    } else {
        size_t i = ((size_t)(bid - 1280) * 256 + threadIdx.x) * 8;
        float4 a = *(const float4*)(x + i);
        float4 b = *(const float4*)(x + i + 4);
        u16 o[8] = {f2bf(a.x), f2bf(a.y), f2bf(a.z), f2bf(a.w),
                    f2bf(b.x), f2bf(b.y), f2bf(b.z), f2bf(b.w)};
        *(int4*)(xb + i) = *(const int4*)o;
    }
}

// ============================================================================
// 2. GEMM split-K=2: C[M,N] fp32 += A[M,K/2-slice]bf16 @ B^T.  128x128 tile,
//    BK=32, glds staging, XOR swizzle. Epilogue = HW fp32 atomics (C must be
//    zeroed first). grid = (N/128, M/128, 2).
// ============================================================================
__global__ __launch_bounds__(256) void gemm_bt(
    const u16* __restrict__ A, const u16* __restrict__ B,
    float* __restrict__ C, int M, int N, int K) {
    __shared__ u16 As[128 * 32];
    __shared__ u16 Bs[128 * 32];
    const int tid = threadIdx.x;
    const int lane = tid & 63, w = tid >> 6;
    const int quad = lane >> 4, l16 = lane & 15;
    const int m0 = blockIdx.y * 128, n0 = blockIdx.x * 128;
    const int kS = blockIdx.z * (K >> 1), kE = kS + (K >> 1);
    const int wm = (w >> 1) * 64, wn = (w & 1) * 64;
    const int sr_ = w * 32 + (lane >> 2);
    const int sg_ = lane & 3;
    u16* Ald = As + w * 1024 + lane * 8;
    u16* Bld = Bs + w * 1024 + lane * 8;

    f32x4 acc[4][4];
    f32x4 zero = {0.f, 0.f, 0.f, 0.f};
    #pragma unroll
    for (int i = 0; i < 4; ++i)
        #pragma unroll
        for (int j = 0; j < 4; ++j) acc[i][j] = zero;

    int aoff[4], boff[4];
    #pragma unroll
    for (int mi = 0; mi < 4; ++mi) {
        int r = wm + mi * 16 + l16;
        aoff[mi] = r * 32 + (quad ^ ((r >> 1) & 3)) * 8;
        int rb = wn + mi * 16 + l16;
        boff[mi] = rb * 32 + (quad ^ ((rb >> 1) & 3)) * 8;
    }

    for (int k0 = kS; k0 < kE; k0 += 32) {
        __syncthreads();
        #pragma unroll
        for (int i = 0; i < 2; ++i) {
            int r = sr_ + i * 16;
            int g = sg_ ^ ((r >> 1) & 3);
            glds16(A + (size_t)(m0 + r) * K + k0 + g * 8, Ald + i * 512);
            glds16(B + (size_t)(n0 + r) * K + k0 + g * 8, Bld + i * 512);
        }
        __syncthreads();
        bf16x8 af[4], bfr[4];
        #pragma unroll
        for (int mi = 0; mi < 4; ++mi) af[mi]  = *(const bf16x8*)(As + aoff[mi]);
        #pragma unroll
        for (int ni = 0; ni < 4; ++ni) bfr[ni] = *(const bf16x8*)(Bs + boff[ni]);
        #pragma unroll
        for (int mi = 0; mi < 4; ++mi)
            #pragma unroll
            for (int ni = 0; ni < 4; ++ni)
                acc[mi][ni] = __builtin_amdgcn_mfma_f32_16x16x32_bf16(af[mi], bfr[ni], acc[mi][ni], 0, 0, 0);
    }
    #pragma unroll
    for (int mi = 0; mi < 4; ++mi)
        #pragma unroll
        for (int ni = 0; ni < 4; ++ni) {
            int rg = m0 + wm + mi * 16 + quad * 4;
            int cg = n0 + wn + ni * 16 + l16;
            float* cp = C + (size_t)rg * N + cg;
            #pragma unroll
            for (int r = 0; r < 4; ++r)
                unsafeAtomicAdd(cp + (size_t)r * N, acc[mi][ni][r]);
        }
}

// ============================================================================
// 3. Fusion: head-RMSNorm + RoPE + gain (pre-scaled by 0.125*log2e for Q);
//    8 tokens/block.
// ============================================================================
__global__ __launch_bounds__(256) void fuse_qkv(
    const float* __restrict__ qkv, const float* __restrict__ gain,
    u16* __restrict__ Qb, u16* __restrict__ Kb, u16* __restrict__ Vt) {
    __shared__ u16 Vs[8][264];
    const int tid = threadIdx.x;
    const int lane = tid & 63, wid = tid >> 6;
    const int lh = lane >> 4, l16 = lane & 15;
    const int T0 = blockIdx.x * 8;
    const int dbase = l16 * 4;
    const bool hi = dbase >= 32;
    const int ibase = hi ? dbase - 32 : dbase;
    const float sgn = hi ? -1.0f : 1.0f;
    const float eps = 1.1920929e-7f;
    const float sc = 0.18033688011112042f;  // 0.125 * log2(e)

    float invf[4];
    #pragma unroll
    for (int j = 0; j < 4; ++j)
        invf[j] = (float)(1.0 / pow(10000.0, (double)(ibase + j) / 32.0));

    #pragma unroll
    for (int i = 0; i < 2; ++i) {
        int tok = T0 + wid * 2 + i;
        int b = tok >> 11, s = tok & 2047;
        float cosv[4], sinv[4];
        #pragma unroll
        for (int j = 0; j < 4; ++j) {
            float fr = (float)s * invf[j];
            cosv[j] = __cosf(fr);
            sinv[j] = __sinf(fr);
        }
        const float* row = qkv + (size_t)tok * 1536;
        #pragma unroll
        for (int p = 0; p < 4; ++p) {
            int h = p * 4 + lh;
            float4 x = *(const float4*)(row + h * 64 + dbase);
            float ss = x.x * x.x + x.y * x.y + x.z * x.z + x.w * x.w;
            #pragma unroll
            for (int m = 1; m < 16; m <<= 1) ss += __shfl_xor(ss, m);
            float rn = 1.0f / sqrtf(ss * (1.0f / 64.0f) + eps);
            float xn0 = x.x * rn, xn1 = x.y * rn, xn2 = x.z * rn, xn3 = x.w * rn;
            float p0 = __shfl_xor(xn0, 8), p1 = __shfl_xor(xn1, 8);
            float p2 = __shfl_xor(xn2, 8), p3 = __shfl_xor(xn3, 8);
            float g = gain[h] * sc;
            u16 o[4] = {f2bf((xn0 * cosv[0] + sgn * p0 * sinv[0]) * g),
                        f2bf((xn1 * cosv[1] + sgn * p1 * sinv[1]) * g),
                        f2bf((xn2 * cosv[2] + sgn * p2 * sinv[2]) * g),
                        f2bf((xn3 * cosv[3] + sgn * p3 * sinv[3]) * g)};
            *(uint2*)(Qb + (((size_t)(b * 16 + h) * 2048 + s) * 64 + dbase)) = *(const uint2*)o;
        }
        {
            float4 x = *(const float4*)(row + 1024 + lh * 64 + dbase);
            float ss = x.x * x.x + x.y * x.y + x.z * x.z + x.w * x.w;
            #pragma unroll
            for (int m = 1; m < 16; m <<= 1) ss += __shfl_xor(ss, m);
            float rn = 1.0f / sqrtf(ss * (1.0f / 64.0f) + eps);
            float xn0 = x.x * rn, xn1 = x.y * rn, xn2 = x.z * rn, xn3 = x.w * rn;
            float p0 = __shfl_xor(xn0, 8), p1 = __shfl_xor(xn1, 8);
            float p2 = __shfl_xor(xn2, 8), p3 = __shfl_xor(xn3, 8);
            u16 o[4] = {f2bf(xn0 * cosv[0] + sgn * p0 * sinv[0]),
                        f2bf(xn1 * cosv[1] + sgn * p1 * sinv[1]),
                        f2bf(xn2 * cosv[2] + sgn * p2 * sinv[2]),
                        f2bf(xn3 * cosv[3] + sgn * p3 * sinv[3])};
            *(uint2*)(Kb + (((size_t)(b * 4 + lh) * 2048 + s) * 64 + dbase)) = *(const uint2*)o;
        }
        {
            float4 x = *(const float4*)(row + 1280 + lh * 64 + dbase);
            u16 o[4] = {f2bf(x.x), f2bf(x.y), f2bf(x.z), f2bf(x.w)};
            int sl = wid * 2 + i;
            *(uint2*)(&Vs[sl][lh * 64 + dbase]) = *(const uint2*)o;
        }
    }
    __syncthreads();
    {
        int kvh = tid >> 6, d = tid & 63;
        int b0 = T0 >> 11, s0 = T0 & 2047;
        u16 tmp[8];
        #pragma unroll
        for (int sl = 0; sl < 8; ++sl) tmp[sl] = Vs[sl][kvh * 64 + d];
        u16* dst = Vt + ((size_t)(b0 * 4 + kvh) * 64 + d) * 2048 + s0;
        *(int4*)(dst) = *(const int4*)(tmp);
    }
}

// ============================================================================
// 4. Flash attention with STATIC per-head softmax max:
//    |score_log2| <= 8*8*0.125*log2e*|gain[h]| = 11.54|g| (rmsnorm'd q,k),
//    so M = 12|g|+1 bounds all scores. p = exp2(s - M) uniformly scales o and
//    l -> o/l exact. Deletes the entire online-softmax path (no m, no max
//    tree, no rescale). 512 thr, 8 waves x one 16-row band, Q-tile 128,
//    split-K chunks of 1024 (grid 32x24).
// ============================================================================
__global__ __launch_bounds__(512, 4) void attn(
    const u16* __restrict__ Qb, const u16* __restrict__ Kb,
    const u16* __restrict__ Vt, const float* __restrict__ gain,
    float* __restrict__ y, float* __restrict__ Opart, float* __restrict__ ml) {
    __shared__ u16 Ks[2][64 * 64];
    __shared__ u16 Vsh[2][64 * 64];
    const int hb = blockIdx.x;
    const int h = hb & 15, b = hb >> 4, kvh = h >> 2;
    const int yid = blockIdx.y;
    int bq, c0; bool partial;
    if (yid < 16) { bq = 15 - (yid >> 1); c0 = (yid & 1) * 16; partial = true; }
    else          { bq = 23 - yid;        c0 = 0;              partial = false; }
    const int nj = partial ? (c0 ? (2 * bq - 14) : 16) : (2 * bq + 2);
    const int q0 = bq * 128;
    const int tid = threadIdx.x, lane = tid & 63, w = tid >> 6;  // w: 0..7
    const int quad = lane >> 4, l16 = lane & 15;
    const float nM = -(12.0f * fabsf(gain[h]) + 1.0f);   // -static max (log2)

    const u16* Qg = Qb + ((size_t)(b * 16 + h) * 2048 + q0) * 64;
    const u16* Kg = Kb + (size_t)(b * 4 + kvh) * 2048 * 64;
    const u16* Vg = Vt + (size_t)(b * 4 + kvh) * 64 * 2048;

    // this wave's Q fragments (rows w*16 + l16)
    const bf16x8 qa0 = *(const bf16x8*)(Qg + (size_t)(w * 16 + l16) * 64 + quad * 8);
    const bf16x8 qa1 = *(const bf16x8*)(Qg + (size_t)(w * 16 + l16) * 64 + 32 + quad * 8);

    // staging: 1 glds16/thread for K and V; source col-group XOR(row&7)
    const int sr = tid >> 3;
    const int sg = (tid & 7) ^ (sr & 7);
    u16* kd[2] = {&Ks[0][0] + tid * 8, &Ks[1][0] + tid * 8};
    u16* vd[2] = {&Vsh[0][0] + tid * 8, &Vsh[1][0] + tid * 8};

    {   // stage tile nj-1
        int c = (c0 + nj - 1) * 64;
        glds16(Kg + (size_t)(c + sr) * 64 + sg * 8, kd[(nj - 1) & 1]);
        glds16(Vg + (size_t)sr * 2048 + c + sg * 8, vd[(nj - 1) & 1]);
    }
    __syncthreads();

    f32x4 o[4];
    f32x4 zero = {0.f, 0.f, 0.f, 0.f};
    #pragma unroll
    for (int t = 0; t < 4; ++t) o[t] = zero;
    float l = 0.f;

    for (int jj = nj - 1; jj >= 0; --jj) {
        if (jj > 0) {
            int c = (c0 + jj - 1) * 64;
            glds16(Kg + (size_t)(c + sr) * 64 + sg * 8, kd[(jj - 1) & 1]);
            glds16(Vg + (size_t)sr * 2048 + c + sg * 8, vd[(jj - 1) & 1]);
        }
        const u16* Kt = (jj & 1) ? &Ks[1][0] : &Ks[0][0];
        const u16* Vl = (jj & 1) ? &Vsh[1][0] : &Vsh[0][0];
        const int d = 8 * bq + w - 4 * (c0 + jj);   // wave-uniform diag tile idx
        if (d >= 0) {
            const int tmax = d < 3 ? d : 3;
            f32x4 st[4];
            #pragma unroll
            for (int t = 0; t < 4; ++t) {
                if (t <= tmax) {
                    int rk = t * 16 + l16;
                    bf16x8 kb0 = *(const bf16x8*)(Kt + rk * 64 + ((quad ^ (rk & 7)) * 8));
                    bf16x8 kb1 = *(const bf16x8*)(Kt + rk * 64 + (((quad + 4) ^ (rk & 7)) * 8));
                    f32x4 s = __builtin_amdgcn_mfma_f32_16x16x32_bf16(kb0, qa0, zero, 0, 0, 0);
                    s = __builtin_amdgcn_mfma_f32_16x16x32_bf16(kb1, qa1, s, 0, 0, 0);
                    if (t == d) {   // diagonal tile: causal mask (uniform branch)
                        #pragma unroll
                        for (int r = 0; r < 4; ++r)
                            if (quad * 4 + r > l16) s[r] = -1e30f;
                    }
                    st[t] = s;
                }
            }
            float rs = 0.f;
            s16x4 pf[4];
            #pragma unroll
            for (int t = 0; t < 4; ++t) {
                if (t <= tmax) {
                    float p0 = __builtin_amdgcn_exp2f(st[t][0] + nM);
                    float p1 = __builtin_amdgcn_exp2f(st[t][1] + nM);
                    float p2 = __builtin_amdgcn_exp2f(st[t][2] + nM);
                    float p3 = __builtin_amdgcn_exp2f(st[t][3] + nM);
                    rs += (p0 + p1) + (p2 + p3);
                    pf[t] = pack_bf4(p0, p1, p2, p3);
                }
            }
            rs += __shfl_xor(rs, 16);
            rs += __shfl_xor(rs, 32);
            l += rs;
            #pragma unroll
            for (int dt = 0; dt < 4; ++dt) {
                int rv = dt * 16 + l16;
                #pragma unroll
                for (int kt = 0; kt < 4; ++kt) {
                    if (kt <= tmax) {
                        int gv = 2 * kt + (quad >> 1);
                        s16x4 va = *(const s16x4*)(Vl + rv * 64 + ((gv ^ (rv & 7)) * 8) + (quad & 1) * 4);
                        o[dt] = MFMA16(va, pf[kt], o[dt]);
                    }
                }
            }
        }
        __syncthreads();
    }

    const int q = w * 16 + l16;
    if (!partial) {
        const float inv = 1.0f / l;
        const size_t row = (size_t)b * 2048 + q0 + q;
        #pragma unroll
        for (int dt = 0; dt < 4; ++dt) {
            f32x4 a = o[dt] * inv;
            *(f32x4*)(&y[row * 1024 + h * 64 + dt * 16 + quad * 4]) = a;
        }
    } else {
        const int slot = (hb * 8 + (bq - 8)) * 2 + (c0 ? 1 : 0);
        float* Op = Opart + (size_t)slot * 8192;
        #pragma unroll
        for (int dt = 0; dt < 4; ++dt)
            *(f32x4*)(Op + q * 64 + dt * 16 + quad * 4) = o[dt];
        if (quad == 0) ml[slot * 128 + q] = l;
    }
}

// ============================================================================
// 5. rmsnorm_merge: rows s<1024 read y; rows s>=1024 combine the two split-K
//    partials (shared static M -> just (x0+x1)/(l0+l1)). Output bf16.
// ============================================================================
__global__ __launch_bounds__(256) void rmsnorm_merge(
    const float* __restrict__ y, const float* __restrict__ Opart,
    const float* __restrict__ ml, u16* __restrict__ yb) {
    __shared__ float red[4];
    const int row = blockIdx.x, tid = threadIdx.x;
    const int b = row >> 11, s = row & 2047;
    float4 v;
    if (s < 1024) {
        v = *(const float4*)(y + (size_t)row * 1024 + tid * 4);
    } else {
        const int bq = s >> 7, q = s & 127;
        const int e = tid * 4, h = e >> 6, dh = e & 63;
        const int slot = ((b * 16 + h) * 8 + (bq - 8)) * 2;
        float l0 = ml[slot * 128 + q];
        float l1 = ml[(slot + 1) * 128 + q];
        float inv = 1.0f / (l0 + l1);
        const float* P0 = Opart + (size_t)slot * 8192 + q * 64 + dh;
        f32x4 x0 = *(const f32x4*)P0;
        f32x4 x1 = *(const f32x4*)(P0 + 8192);
        f32x4 r = (x0 + x1) * inv;
        v.x = r[0]; v.y = r[1]; v.z = r[2]; v.w = r[3];
    }
    float ss = v.x * v.x + v.y * v.y + v.z * v.z + v.w * v.w;
    #pragma unroll
    for (int m = 1; m < 64; m <<= 1) ss += __shfl_xor(ss, m);
    if ((tid & 63) == 0) red[tid >> 6] = ss;
    __syncthreads();
    float tot = red[0] + red[1] + red[2] + red[3];
    float rn = 1.0f / sqrtf(tot * (1.0f / 1024.0f) + 1.1920929e-7f);
    u16 o[4] = {f2bf(v.x * rn), f2bf(v.y * rn), f2bf(v.z * rn), f2bf(v.w * rn)};
    *(uint2*)(yb + (size_t)row * 1024 + tid * 4) = *(const uint2*)o;
}

// ============================================================================
// launch — workspace (peak ~48.5 MB), layout as R6 (ml now float):
//   [0,      2.10M)  wproj_b   [2.10M,10.49M) xb/Qb/yb   [10.49M,13.64M)
//   wqkv_b->Kb   [12.58M,14.68M) Vt   [14.68M,39.85M) qkv/y
//   [31.46M,48.23M) Opart   [48.23M,48.50M) ml
// ============================================================================
extern "C" void kernel_launch(void* const* d_in, const int* in_sizes, int n_in,
                              void* d_out, int out_size, void* d_ws, size_t ws_size,
                              hipStream_t stream) {
    const float* x      = (const float*)d_in[0];
    const float* w_qkv  = (const float*)d_in[1];
    const float* w_proj = (const float*)d_in[2];
    const float* q_gain = (const float*)d_in[3];
    float* out = (float*)d_out;
    char* ws = (char*)d_ws;

    u16*   wproj_b = (u16*)(ws);
    u16*   xb      = (u16*)(ws + 2097152);
    u16*   Qb      = (u16*)(ws + 2097152);
    u16*   yb      = (u16*)(ws + 2097152);
    u16*   wqkv_b  = (u16*)(ws + 10485760);
    u16*   Kb      = (u16*)(ws + 10485760);
    u16*   Vt      = (u16*)(ws + 12582912);
    float* qkv     = (float*)(ws + 14680064);
    float* y       = (float*)(ws + 14680064);
    float* Opart   = (float*)(ws + 31457280);
    float* mlb     = (float*)(ws + 48234496);

    // zero split-K accumulation targets (graph-capturable memset nodes)
    hipMemsetAsync(qkv, 0, 25165824, stream);
    hipMemsetAsync(out, 0, (size_t)out_size * 4, stream);

    prep<<<3328, 256, 0, stream>>>(w_qkv, w_proj, x, wqkv_b, wproj_b, xb);
    gemm_bt<<<dim3(12, 32, 2), 256, 0, stream>>>(xb, wqkv_b, qkv, 4096, 1536, 1024);
    fuse_qkv<<<512, 256, 0, stream>>>(qkv, q_gain, Qb, Kb, Vt);
    attn<<<dim3(32, 24), 512, 0, stream>>>(Qb, Kb, Vt, q_gain, y, Opart, mlb);
    rmsnorm_merge<<<4096, 256, 0, stream>>>(y, Opart, mlb, yb);
    gemm_bt<<<dim3(8, 32, 2), 256, 0, stream>>>(yb, wproj_b, out, 4096, 1024, 1024);
}

// Round 8
// 189.028 us; speedup vs baseline: 1.2963x; 1.2963x over previous
//
#include <hip/hip_runtime.h>
#include <cstdint>

typedef unsigned short u16;
typedef __bf16 bf16x8 __attribute__((ext_vector_type(8)));
typedef short s16x4 __attribute__((ext_vector_type(4)));
typedef int s32x2 __attribute__((ext_vector_type(2)));
typedef float f32x4 __attribute__((ext_vector_type(4)));

// ---- bf16 helpers (RTNE, matching XLA/ml_dtypes) ----
__device__ __forceinline__ u16 f2bf(float f) {
    unsigned u = __float_as_uint(f);
    u = (u + 0x7fffu + ((u >> 16) & 1u)) >> 16;
    return (u16)u;
}
__device__ __forceinline__ float bf2f(u16 h) {
    return __uint_as_float(((unsigned)h) << 16);
}

// async global->LDS, 16B per lane; LDS dest = wave-uniform base + lane*16
__device__ __forceinline__ void glds16(const u16* g, u16* l) {
    __builtin_amdgcn_global_load_lds(
        (const __attribute__((address_space(1))) void*)g,
        (__attribute__((address_space(3))) void*)l, 16, 0, 0);
}

// pack 4 positive floats -> 4 bf16 (round-half-up; ties-only diff vs RTNE)
__device__ __forceinline__ s16x4 pack_bf4(float p0, float p1, float p2, float p3) {
    unsigned a0 = __float_as_uint(p0) + 0x8000u;
    unsigned a1 = __float_as_uint(p1) + 0x8000u;
    unsigned a2 = __float_as_uint(p2) + 0x8000u;
    unsigned a3 = __float_as_uint(p3) + 0x8000u;
    s32x2 pk = {(int)__builtin_amdgcn_perm(a1, a0, 0x07060302u),
                (int)__builtin_amdgcn_perm(a3, a2, 0x07060302u)};
    return __builtin_bit_cast(s16x4, pk);
}

#if __has_builtin(__builtin_amdgcn_mfma_f32_16x16x16bf16_1k)
#define MFMA16(a, b, c) __builtin_amdgcn_mfma_f32_16x16x16bf16_1k(a, b, c, 0, 0, 0)
#else
static __device__ __forceinline__ f32x4 mfma16_asm(s16x4 a, s16x4 b, f32x4 c) {
    asm("v_mfma_f32_16x16x16_bf16 %0, %1, %2, %0" : "+v"(c) : "v"(a), "v"(b));
    return c;
}
#define MFMA16(a, b, c) mfma16_asm(a, b, c)
#endif

// ============================================================================
// 1. prep: ternary-quantize both weights (8 elems/lane) + cast x to bf16.
//    GRID = 1280 quant + 2048 cast = 3328.
// ============================================================================
__global__ __launch_bounds__(256) void prep(
    const float* __restrict__ w_qkv, const float* __restrict__ w_proj,
    const float* __restrict__ x,
    u16* __restrict__ wqkv_b, u16* __restrict__ wproj_b, u16* __restrict__ xb) {
    int bid = blockIdx.x;
    if (bid < 1280) {
        const float* w; u16* o; size_t base;
        if (bid < 768) { w = w_qkv; o = wqkv_b; base = (size_t)bid * 2048; }
        else { w = w_proj; o = wproj_b; base = (size_t)(bid - 768) * 2048; }
        size_t i = base + (size_t)threadIdx.x * 8;
        float4 A = *(const float4*)(w + i);
        float4 B = *(const float4*)(w + i + 4);
        float wf[8] = {A.x, A.y, A.z, A.w, B.x, B.y, B.z, B.w};
        float wbf[8], ab[8];
        #pragma unroll
        for (int e = 0; e < 8; ++e) { wbf[e] = bf2f(f2bf(wf[e])); ab[e] = fabsf(wbf[e]); }
        float s = ((ab[0] + ab[1]) + (ab[2] + ab[3])) + ((ab[4] + ab[5]) + (ab[6] + ab[7]));
        s += __shfl_xor(s, 1);
        s += __shfl_xor(s, 2);
        s += __shfl_xor(s, 4);   // 8-lane cluster = one 64-elem group
        float scale = bf2f(f2bf(s * (1.0f / 64.0f)));
        if (scale < 1e-8f) scale = 1e-8f;
        u16 ov[8];
        #pragma unroll
        for (int e = 0; e < 8; ++e) {
            float t = bf2f(f2bf(wbf[e] / scale));
            float q = rintf(t);
            q = fminf(1.0f, fmaxf(-1.0f, q));
            float d = bf2f(f2bf(q * scale - wbf[e]));
            ov[e] = f2bf(wbf[e] + d);
        }
        *(int4*)(o + i) = *(const int4*)ov;
    } else {
        size_t i = ((size_t)(bid - 1280) * 256 + threadIdx.x) * 8;
        float4 a = *(const float4*)(x + i);
        float4 b = *(const float4*)(x + i + 4);
        u16 o[8] = {f2bf(a.x), f2bf(a.y), f2bf(a.z), f2bf(a.w),
                    f2bf(b.x), f2bf(b.y), f2bf(b.z), f2bf(b.w)};
        *(int4*)(xb + i) = *(const int4*)o;
    }
}

// ============================================================================
// 2. GEMM: C[M,N] fp32 = A[M,K]bf16 @ B[N,K]bf16^T.  128M x 64N tile, BK=32,
//    DOUBLE-BUFFERED glds staging with ONE barrier per K-iter (attn-style):
//    glds for tile k+1 flies while MFMAs consume tile k. 24 KB LDS ->
//    grid 768/512 blocks = 3/2 per CU fill the barrier drain. Direct stores.
// ============================================================================
__global__ __launch_bounds__(256) void gemm_bt(
    const u16* __restrict__ A, const u16* __restrict__ B,
    float* __restrict__ C, int M, int N, int K) {
    __shared__ u16 As[2][128 * 32];
    __shared__ u16 Bs[2][64 * 32];
    const int tid = threadIdx.x;
    const int lane = tid & 63, w = tid >> 6;
    const int quad = lane >> 4, l16 = lane & 15;
    const int m0 = blockIdx.y * 128, n0 = blockIdx.x * 64;
    const int wm = (w >> 1) * 64, wn = (w & 1) * 32;   // wave: 64M x 32N

    // staging geometry (glds: wave-uniform LDS base + lane*16B)
    const int sra = w * 16 + (lane >> 2);   // A rows: +i*64
    const int srb = tid >> 2;               // B row (64 rows, 1 instr)
    const int sg4 = lane & 3;

    f32x4 acc[4][2];
    f32x4 zero = {0.f, 0.f, 0.f, 0.f};
    #pragma unroll
    for (int i = 0; i < 4; ++i) { acc[i][0] = zero; acc[i][1] = zero; }

    // read-side swizzled element offsets
    int aoff[4], boff[2];
    #pragma unroll
    for (int mi = 0; mi < 4; ++mi) {
        int r = wm + mi * 16 + l16;
        aoff[mi] = r * 32 + (quad ^ ((r >> 1) & 3)) * 8;
    }
    #pragma unroll
    for (int ni = 0; ni < 2; ++ni) {
        int r = wn + ni * 16 + l16;
        boff[ni] = r * 32 + (quad ^ ((r >> 1) & 3)) * 8;
    }

    const int nk = K >> 5;
    // stage tile 0 into buf 0
    #pragma unroll
    for (int i = 0; i < 2; ++i) {
        int r = sra + i * 64;
        int g = sg4 ^ ((r >> 1) & 3);
        glds16(A + (size_t)(m0 + r) * K + g * 8, &As[0][0] + (w * 16 + i * 64) * 32 + lane * 8);
    }
    {
        int g = sg4 ^ ((srb >> 1) & 3);
        glds16(B + (size_t)(n0 + srb) * K + g * 8, &Bs[0][0] + w * 512 + lane * 8);
    }
    __syncthreads();

    for (int kt = 0; kt < nk; ++kt) {
        if (kt + 1 < nk) {
            int k0 = (kt + 1) * 32, bi = (kt + 1) & 1;
            #pragma unroll
            for (int i = 0; i < 2; ++i) {
                int r = sra + i * 64;
                int g = sg4 ^ ((r >> 1) & 3);
                glds16(A + (size_t)(m0 + r) * K + k0 + g * 8, &As[bi][0] + (w * 16 + i * 64) * 32 + lane * 8);
            }
            int g = sg4 ^ ((srb >> 1) & 3);
            glds16(B + (size_t)(n0 + srb) * K + k0 + g * 8, &Bs[bi][0] + w * 512 + lane * 8);
        }
        const u16* as = &As[kt & 1][0];
        const u16* bs = &Bs[kt & 1][0];
        bf16x8 af[4], bfr[2];
        #pragma unroll
        for (int mi = 0; mi < 4; ++mi) af[mi]  = *(const bf16x8*)(as + aoff[mi]);
        #pragma unroll
        for (int ni = 0; ni < 2; ++ni) bfr[ni] = *(const bf16x8*)(bs + boff[ni]);
        #pragma unroll
        for (int mi = 0; mi < 4; ++mi)
            #pragma unroll
            for (int ni = 0; ni < 2; ++ni)
                acc[mi][ni] = __builtin_amdgcn_mfma_f32_16x16x32_bf16(af[mi], bfr[ni], acc[mi][ni], 0, 0, 0);
        __syncthreads();
    }
    #pragma unroll
    for (int mi = 0; mi < 4; ++mi)
        #pragma unroll
        for (int ni = 0; ni < 2; ++ni) {
            int rg = m0 + wm + mi * 16 + quad * 4;
            int cg = n0 + wn + ni * 16 + l16;
            float* cp = C + (size_t)rg * N + cg;
            #pragma unroll
            for (int r = 0; r < 4; ++r) cp[(size_t)r * N] = acc[mi][ni][r];
        }
}

// ============================================================================
// 3. Fusion: head-RMSNorm + RoPE + gain (pre-scaled by 0.125*log2e for Q);
//    8 tokens/block.
// ============================================================================
__global__ __launch_bounds__(256) void fuse_qkv(
    const float* __restrict__ qkv, const float* __restrict__ gain,
    u16* __restrict__ Qb, u16* __restrict__ Kb, u16* __restrict__ Vt) {
    __shared__ u16 Vs[8][264];
    const int tid = threadIdx.x;
    const int lane = tid & 63, wid = tid >> 6;
    const int lh = lane >> 4, l16 = lane & 15;
    const int T0 = blockIdx.x * 8;
    const int dbase = l16 * 4;
    const bool hi = dbase >= 32;
    const int ibase = hi ? dbase - 32 : dbase;
    const float sgn = hi ? -1.0f : 1.0f;
    const float eps = 1.1920929e-7f;
    const float sc = 0.18033688011112042f;  // 0.125 * log2(e)

    float invf[4];
    #pragma unroll
    for (int j = 0; j < 4; ++j)
        invf[j] = (float)(1.0 / pow(10000.0, (double)(ibase + j) / 32.0));

    #pragma unroll
    for (int i = 0; i < 2; ++i) {
        int tok = T0 + wid * 2 + i;
        int b = tok >> 11, s = tok & 2047;
        float cosv[4], sinv[4];
        #pragma unroll
        for (int j = 0; j < 4; ++j) {
            float fr = (float)s * invf[j];
            cosv[j] = __cosf(fr);
            sinv[j] = __sinf(fr);
        }
        const float* row = qkv + (size_t)tok * 1536;
        #pragma unroll
        for (int p = 0; p < 4; ++p) {
            int h = p * 4 + lh;
            float4 x = *(const float4*)(row + h * 64 + dbase);
            float ss = x.x * x.x + x.y * x.y + x.z * x.z + x.w * x.w;
            #pragma unroll
            for (int m = 1; m < 16; m <<= 1) ss += __shfl_xor(ss, m);
            float rn = 1.0f / sqrtf(ss * (1.0f / 64.0f) + eps);
            float xn0 = x.x * rn, xn1 = x.y * rn, xn2 = x.z * rn, xn3 = x.w * rn;
            float p0 = __shfl_xor(xn0, 8), p1 = __shfl_xor(xn1, 8);
            float p2 = __shfl_xor(xn2, 8), p3 = __shfl_xor(xn3, 8);
            float g = gain[h] * sc;
            u16 o[4] = {f2bf((xn0 * cosv[0] + sgn * p0 * sinv[0]) * g),
                        f2bf((xn1 * cosv[1] + sgn * p1 * sinv[1]) * g),
                        f2bf((xn2 * cosv[2] + sgn * p2 * sinv[2]) * g),
                        f2bf((xn3 * cosv[3] + sgn * p3 * sinv[3]) * g)};
            *(uint2*)(Qb + (((size_t)(b * 16 + h) * 2048 + s) * 64 + dbase)) = *(const uint2*)o;
        }
        {
            float4 x = *(const float4*)(row + 1024 + lh * 64 + dbase);
            float ss = x.x * x.x + x.y * x.y + x.z * x.z + x.w * x.w;
            #pragma unroll
            for (int m = 1; m < 16; m <<= 1) ss += __shfl_xor(ss, m);
            float rn = 1.0f / sqrtf(ss * (1.0f / 64.0f) + eps);
            float xn0 = x.x * rn, xn1 = x.y * rn, xn2 = x.z * rn, xn3 = x.w * rn;
            float p0 = __shfl_xor(xn0, 8), p1 = __shfl_xor(xn1, 8);
            float p2 = __shfl_xor(xn2, 8), p3 = __shfl_xor(xn3, 8);
            u16 o[4] = {f2bf(xn0 * cosv[0] + sgn * p0 * sinv[0]),
                        f2bf(xn1 * cosv[1] + sgn * p1 * sinv[1]),
                        f2bf(xn2 * cosv[2] + sgn * p2 * sinv[2]),
                        f2bf(xn3 * cosv[3] + sgn * p3 * sinv[3])};
            *(uint2*)(Kb + (((size_t)(b * 4 + lh) * 2048 + s) * 64 + dbase)) = *(const uint2*)o;
        }
        {
            float4 x = *(const float4*)(row + 1280 + lh * 64 + dbase);
            u16 o[4] = {f2bf(x.x), f2bf(x.y), f2bf(x.z), f2bf(x.w)};
            int sl = wid * 2 + i;
            *(uint2*)(&Vs[sl][lh * 64 + dbase]) = *(const uint2*)o;
        }
    }
    __syncthreads();
    {
        int kvh = tid >> 6, d = tid & 63;
        int b0 = T0 >> 11, s0 = T0 & 2047;
        u16 tmp[8];
        #pragma unroll
        for (int sl = 0; sl < 8; ++sl) tmp[sl] = Vs[sl][kvh * 64 + d];
        u16* dst = Vt + ((size_t)(b0 * 4 + kvh) * 64 + d) * 2048 + s0;
        *(int4*)(dst) = *(const int4*)(tmp);
    }
}

// ============================================================================
// 4. Flash attention with STATIC per-head softmax max (|score_log2| <=
//    11.54|gain|, M = 12|g|+1; ratio o/l exact). 512 thr, 8 waves x one
//    16-row band, Q-tile 128, split-K chunks of 1024 (grid 32x24).
// ============================================================================
__global__ __launch_bounds__(512, 4) void attn(
    const u16* __restrict__ Qb, const u16* __restrict__ Kb,
    const u16* __restrict__ Vt, const float* __restrict__ gain,
    float* __restrict__ y, float* __restrict__ Opart, float* __restrict__ ml) {
    __shared__ u16 Ks[2][64 * 64];
    __shared__ u16 Vsh[2][64 * 64];
    const int hb = blockIdx.x;
    const int h = hb & 15, b = hb >> 4, kvh = h >> 2;
    const int yid = blockIdx.y;
    int bq, c0; bool partial;
    if (yid < 16) { bq = 15 - (yid >> 1); c0 = (yid & 1) * 16; partial = true; }
    else          { bq = 23 - yid;        c0 = 0;              partial = false; }
    const int nj = partial ? (c0 ? (2 * bq - 14) : 16) : (2 * bq + 2);
    const int q0 = bq * 128;
    const int tid = threadIdx.x, lane = tid & 63, w = tid >> 6;  // w: 0..7
    const int quad = lane >> 4, l16 = lane & 15;
    const float nM = -(12.0f * fabsf(gain[h]) + 1.0f);   // -static max (log2)

    const u16* Qg = Qb + ((size_t)(b * 16 + h) * 2048 + q0) * 64;
    const u16* Kg = Kb + (size_t)(b * 4 + kvh) * 2048 * 64;
    const u16* Vg = Vt + (size_t)(b * 4 + kvh) * 64 * 2048;

    const bf16x8 qa0 = *(const bf16x8*)(Qg + (size_t)(w * 16 + l16) * 64 + quad * 8);
    const bf16x8 qa1 = *(const bf16x8*)(Qg + (size_t)(w * 16 + l16) * 64 + 32 + quad * 8);

    const int sr = tid >> 3;
    const int sg = (tid & 7) ^ (sr & 7);
    u16* kd[2] = {&Ks[0][0] + tid * 8, &Ks[1][0] + tid * 8};
    u16* vd[2] = {&Vsh[0][0] + tid * 8, &Vsh[1][0] + tid * 8};

    {   // stage tile nj-1
        int c = (c0 + nj - 1) * 64;
        glds16(Kg + (size_t)(c + sr) * 64 + sg * 8, kd[(nj - 1) & 1]);
        glds16(Vg + (size_t)sr * 2048 + c + sg * 8, vd[(nj - 1) & 1]);
    }
    __syncthreads();

    f32x4 o[4];
    f32x4 zero = {0.f, 0.f, 0.f, 0.f};
    #pragma unroll
    for (int t = 0; t < 4; ++t) o[t] = zero;
    float l = 0.f;

    for (int jj = nj - 1; jj >= 0; --jj) {
        if (jj > 0) {
            int c = (c0 + jj - 1) * 64;
            glds16(Kg + (size_t)(c + sr) * 64 + sg * 8, kd[(jj - 1) & 1]);
            glds16(Vg + (size_t)sr * 2048 + c + sg * 8, vd[(jj - 1) & 1]);
        }
        const u16* Kt = (jj & 1) ? &Ks[1][0] : &Ks[0][0];
        const u16* Vl = (jj & 1) ? &Vsh[1][0] : &Vsh[0][0];
        const int d = 8 * bq + w - 4 * (c0 + jj);   // wave-uniform diag tile idx
        if (d >= 0) {
            const int tmax = d < 3 ? d : 3;
            f32x4 st[4];
            #pragma unroll
            for (int t = 0; t < 4; ++t) {
                if (t <= tmax) {
                    int rk = t * 16 + l16;
                    bf16x8 kb0 = *(const bf16x8*)(Kt + rk * 64 + ((quad ^ (rk & 7)) * 8));
                    bf16x8 kb1 = *(const bf16x8*)(Kt + rk * 64 + (((quad + 4) ^ (rk & 7)) * 8));
                    f32x4 s = __builtin_amdgcn_mfma_f32_16x16x32_bf16(kb0, qa0, zero, 0, 0, 0);
                    s = __builtin_amdgcn_mfma_f32_16x16x32_bf16(kb1, qa1, s, 0, 0, 0);
                    if (t == d) {   // diagonal tile: causal mask (uniform branch)
                        #pragma unroll
                        for (int r = 0; r < 4; ++r)
                            if (quad * 4 + r > l16) s[r] = -1e30f;
                    }
                    st[t] = s;
                }
            }
            float rs = 0.f;
            s16x4 pf[4];
            #pragma unroll
            for (int t = 0; t < 4; ++t) {
                if (t <= tmax) {
                    float p0 = __builtin_amdgcn_exp2f(st[t][0] + nM);
                    float p1 = __builtin_amdgcn_exp2f(st[t][1] + nM);
                    float p2 = __builtin_amdgcn_exp2f(st[t][2] + nM);
                    float p3 = __builtin_amdgcn_exp2f(st[t][3] + nM);
                    rs += (p0 + p1) + (p2 + p3);
                    pf[t] = pack_bf4(p0, p1, p2, p3);
                }
            }
            rs += __shfl_xor(rs, 16);
            rs += __shfl_xor(rs, 32);
            l += rs;
            #pragma unroll
            for (int dt = 0; dt < 4; ++dt) {
                int rv = dt * 16 + l16;
                #pragma unroll
                for (int kt = 0; kt < 4; ++kt) {
                    if (kt <= tmax) {
                        int gv = 2 * kt + (quad >> 1);
                        s16x4 va = *(const s16x4*)(Vl + rv * 64 + ((gv ^ (rv & 7)) * 8) + (quad & 1) * 4);
                        o[dt] = MFMA16(va, pf[kt], o[dt]);
                    }
                }
            }
        }
        __syncthreads();
    }

    const int q = w * 16 + l16;
    if (!partial) {
        const float inv = 1.0f / l;
        const size_t row = (size_t)b * 2048 + q0 + q;
        #pragma unroll
        for (int dt = 0; dt < 4; ++dt) {
            f32x4 a = o[dt] * inv;
            *(f32x4*)(&y[row * 1024 + h * 64 + dt * 16 + quad * 4]) = a;
        }
    } else {
        const int slot = (hb * 8 + (bq - 8)) * 2 + (c0 ? 1 : 0);
        float* Op = Opart + (size_t)slot * 8192;
        #pragma unroll
        for (int dt = 0; dt < 4; ++dt)
            *(f32x4*)(Op + q * 64 + dt * 16 + quad * 4) = o[dt];
        if (quad == 0) ml[slot * 128 + q] = l;
    }
}

// ============================================================================
// 5. rmsnorm_merge: rows s<1024 read y; rows s>=1024 combine the two split-K
//    partials (shared static M -> (x0+x1)/(l0+l1)). Output bf16.
// ============================================================================
__global__ __launch_bounds__(256) void rmsnorm_merge(
    const float* __restrict__ y, const float* __restrict__ Opart,
    const float* __restrict__ ml, u16* __restrict__ yb) {
    __shared__ float red[4];
    const int row = blockIdx.x, tid = threadIdx.x;
    const int b = row >> 11, s = row & 2047;
    float4 v;
    if (s < 1024) {
        v = *(const float4*)(y + (size_t)row * 1024 + tid * 4);
    } else {
        const int bq = s >> 7, q = s & 127;
        const int e = tid * 4, h = e >> 6, dh = e & 63;
        const int slot = ((b * 16 + h) * 8 + (bq - 8)) * 2;
        float l0 = ml[slot * 128 + q];
        float l1 = ml[(slot + 1) * 128 + q];
        float inv = 1.0f / (l0 + l1);
        const float* P0 = Opart + (size_t)slot * 8192 + q * 64 + dh;
        f32x4 x0 = *(const f32x4*)P0;
        f32x4 x1 = *(const f32x4*)(P0 + 8192);
        f32x4 r = (x0 + x1) * inv;
        v.x = r[0]; v.y = r[1]; v.z = r[2]; v.w = r[3];
    }
    float ss = v.x * v.x + v.y * v.y + v.z * v.z + v.w * v.w;
    #pragma unroll
    for (int m = 1; m < 64; m <<= 1) ss += __shfl_xor(ss, m);
    if ((tid & 63) == 0) red[tid >> 6] = ss;
    __syncthreads();
    float tot = red[0] + red[1] + red[2] + red[3];
    float rn = 1.0f / sqrtf(tot * (1.0f / 1024.0f) + 1.1920929e-7f);
    u16 o[4] = {f2bf(v.x * rn), f2bf(v.y * rn), f2bf(v.z * rn), f2bf(v.w * rn)};
    *(uint2*)(yb + (size_t)row * 1024 + tid * 4) = *(const uint2*)o;
}

// ============================================================================
// launch — workspace (peak ~48.5 MB):
//   [0,      2.10M)  wproj_b   [2.10M,10.49M) xb/Qb/yb   [10.49M,13.64M)
//   wqkv_b->Kb   [12.58M,14.68M) Vt   [14.68M,39.85M) qkv/y
//   [31.46M,48.23M) Opart   [48.23M,48.50M) ml
// ============================================================================
extern "C" void kernel_launch(void* const* d_in, const int* in_sizes, int n_in,
                              void* d_out, int out_size, void* d_ws, size_t ws_size,
                              hipStream_t stream) {
    const float* x      = (const float*)d_in[0];
    const float* w_qkv  = (const float*)d_in[1];
    const float* w_proj = (const float*)d_in[2];
    const float* q_gain = (const float*)d_in[3];
    float* out = (float*)d_out;
    char* ws = (char*)d_ws;

    u16*   wproj_b = (u16*)(ws);
    u16*   xb      = (u16*)(ws + 2097152);
    u16*   Qb      = (u16*)(ws + 2097152);
    u16*   yb      = (u16*)(ws + 2097152);
    u16*   wqkv_b  = (u16*)(ws + 10485760);
    u16*   Kb      = (u16*)(ws + 10485760);
    u16*   Vt      = (u16*)(ws + 12582912);
    float* qkv     = (float*)(ws + 14680064);
    float* y       = (float*)(ws + 14680064);
    float* Opart   = (float*)(ws + 31457280);
    float* mlb     = (float*)(ws + 48234496);

    prep<<<3328, 256, 0, stream>>>(w_qkv, w_proj, x, wqkv_b, wproj_b, xb);
    gemm_bt<<<dim3(24, 32), 256, 0, stream>>>(xb, wqkv_b, qkv, 4096, 1536, 1024);
    fuse_qkv<<<512, 256, 0, stream>>>(qkv, q_gain, Qb, Kb, Vt);
    attn<<<dim3(32, 24), 512, 0, stream>>>(Qb, Kb, Vt, q_gain, y, Opart, mlb);
    rmsnorm_merge<<<4096, 256, 0, stream>>>(y, Opart, mlb, yb);
    gemm_bt<<<dim3(16, 32), 256, 0, stream>>>(yb, wproj_b, out, 4096, 1024, 1024);
}

// Round 9
// 186.587 us; speedup vs baseline: 1.3133x; 1.0131x over previous
//
#include <hip/hip_runtime.h>
#include <cstdint>

typedef unsigned short u16;
typedef __bf16 bf16x8 __attribute__((ext_vector_type(8)));
typedef short s16x4 __attribute__((ext_vector_type(4)));
typedef int s32x2 __attribute__((ext_vector_type(2)));
typedef float f32x4 __attribute__((ext_vector_type(4)));

// ---- bf16 helpers (RTNE, matching XLA/ml_dtypes) ----
__device__ __forceinline__ u16 f2bf(float f) {
    unsigned u = __float_as_uint(f);
    u = (u + 0x7fffu + ((u >> 16) & 1u)) >> 16;
    return (u16)u;
}
__device__ __forceinline__ float bf2f(u16 h) {
    return __uint_as_float(((unsigned)h) << 16);
}

// async global->LDS, 16B per lane; LDS dest = wave-uniform base + lane*16
__device__ __forceinline__ void glds16(const u16* g, u16* l) {
    __builtin_amdgcn_global_load_lds(
        (const __attribute__((address_space(1))) void*)g,
        (__attribute__((address_space(3))) void*)l, 16, 0, 0);
}

// pack 4 positive floats -> 4 bf16 (round-half-up; ties-only diff vs RTNE)
__device__ __forceinline__ s16x4 pack_bf4(float p0, float p1, float p2, float p3) {
    unsigned a0 = __float_as_uint(p0) + 0x8000u;
    unsigned a1 = __float_as_uint(p1) + 0x8000u;
    unsigned a2 = __float_as_uint(p2) + 0x8000u;
    unsigned a3 = __float_as_uint(p3) + 0x8000u;
    s32x2 pk = {(int)__builtin_amdgcn_perm(a1, a0, 0x07060302u),
                (int)__builtin_amdgcn_perm(a3, a2, 0x07060302u)};
    return __builtin_bit_cast(s16x4, pk);
}

#if __has_builtin(__builtin_amdgcn_mfma_f32_16x16x16bf16_1k)
#define MFMA16(a, b, c) __builtin_amdgcn_mfma_f32_16x16x16bf16_1k(a, b, c, 0, 0, 0)
#else
static __device__ __forceinline__ f32x4 mfma16_asm(s16x4 a, s16x4 b, f32x4 c) {
    asm("v_mfma_f32_16x16x16_bf16 %0, %1, %2, %0" : "+v"(c) : "v"(a), "v"(b));
    return c;
}
#define MFMA16(a, b, c) mfma16_asm(a, b, c)
#endif

// ============================================================================
// 1. prep: ternary-quantize both weights (8 elems/lane) + cast x to bf16.
//    GRID = 1280 quant + 2048 cast = 3328.
// ============================================================================
__global__ __launch_bounds__(256) void prep(
    const float* __restrict__ w_qkv, const float* __restrict__ w_proj,
    const float* __restrict__ x,
    u16* __restrict__ wqkv_b, u16* __restrict__ wproj_b, u16* __restrict__ xb) {
    int bid = blockIdx.x;
    if (bid < 1280) {
        const float* w; u16* o; size_t base;
        if (bid < 768) { w = w_qkv; o = wqkv_b; base = (size_t)bid * 2048; }
        else { w = w_proj; o = wproj_b; base = (size_t)(bid - 768) * 2048; }
        size_t i = base + (size_t)threadIdx.x * 8;
        float4 A = *(const float4*)(w + i);
        float4 B = *(const float4*)(w + i + 4);
        float wf[8] = {A.x, A.y, A.z, A.w, B.x, B.y, B.z, B.w};
        float wbf[8], ab[8];
        #pragma unroll
        for (int e = 0; e < 8; ++e) { wbf[e] = bf2f(f2bf(wf[e])); ab[e] = fabsf(wbf[e]); }
        float s = ((ab[0] + ab[1]) + (ab[2] + ab[3])) + ((ab[4] + ab[5]) + (ab[6] + ab[7]));
        s += __shfl_xor(s, 1);
        s += __shfl_xor(s, 2);
        s += __shfl_xor(s, 4);   // 8-lane cluster = one 64-elem group
        float scale = bf2f(f2bf(s * (1.0f / 64.0f)));
        if (scale < 1e-8f) scale = 1e-8f;
        u16 ov[8];
        #pragma unroll
        for (int e = 0; e < 8; ++e) {
            float t = bf2f(f2bf(wbf[e] / scale));
            float q = rintf(t);
            q = fminf(1.0f, fmaxf(-1.0f, q));
            float d = bf2f(f2bf(q * scale - wbf[e]));
            ov[e] = f2bf(wbf[e] + d);
        }
        *(int4*)(o + i) = *(const int4*)ov;
    } else {
        size_t i = ((size_t)(bid - 1280) * 256 + threadIdx.x) * 8;
        float4 a = *(const float4*)(x + i);
        float4 b = *(const float4*)(x + i + 4);
        u16 o[8] = {f2bf(a.x), f2bf(a.y), f2bf(a.z), f2bf(a.w),
                    f2bf(b.x), f2bf(b.y), f2bf(b.z), f2bf(b.w)};
        *(int4*)(xb + i) = *(const int4*)o;
    }
}

// ============================================================================
// 2. gemm_qkv: xb[4096x1024] @ wqkv^T with FUSED RMSNorm+RoPE+gain epilogue.
//    Tile 256M x 64N (one head per block), 4 waves each 64x64, dbuf glds,
//    one barrier/iter. bx<16: Q head; 16..19: K head; 20..23: V head.
//    V blocks use SWAPPED mfma operands -> acc holds D[d][s] -> Vt stores
//    are s-coalesced (no transpose pass). Q/K: RMSNorm reduce is in-lane +
//    xor<=8 shuffles; RoPE partner (d,d+32) = acc[mi][ni] vs acc[mi][ni+2].
// ============================================================================
__global__ __launch_bounds__(256) void gemm_qkv(
    const u16* __restrict__ A, const u16* __restrict__ B,
    const float* __restrict__ gain,
    u16* __restrict__ Qb, u16* __restrict__ Kb, u16* __restrict__ Vt) {
    __shared__ u16 As[2][256 * 32];
    __shared__ u16 Bs[2][64 * 32];
    const int tid = threadIdx.x;
    const int lane = tid & 63, w = tid >> 6;
    const int quad = lane >> 4, l16 = lane & 15;
    const int bx = blockIdx.x, by = blockIdx.y;
    const int n0 = bx * 64, t0 = by * 256;
    const bool vblk = bx >= 20;
    const int K = 1024, nk = 32;
    const int b = by >> 3;           // batch (256 | 2048)

    // staging geometry
    const int sra = w * 16 + (lane >> 2);   // A local row, +i*64
    const int srb = tid >> 2;               // B local row (0..63)
    const int sg4 = lane & 3;

    f32x4 acc[4][4];
    f32x4 zero = {0.f, 0.f, 0.f, 0.f};
    #pragma unroll
    for (int i = 0; i < 4; ++i)
        #pragma unroll
        for (int j = 0; j < 4; ++j) acc[i][j] = zero;

    int aoff[4], boff[4];
    #pragma unroll
    for (int mi = 0; mi < 4; ++mi) {
        int r = w * 64 + mi * 16 + l16;
        aoff[mi] = r * 32 + (quad ^ ((r >> 1) & 3)) * 8;
    }
    #pragma unroll
    for (int ni = 0; ni < 4; ++ni) {
        int rb = ni * 16 + l16;
        boff[ni] = rb * 32 + (quad ^ ((rb >> 1) & 3)) * 8;
    }

    // stage tile 0
    #pragma unroll
    for (int i = 0; i < 4; ++i) {
        int r = sra + i * 64;
        int g = sg4 ^ ((r >> 1) & 3);
        glds16(A + (size_t)(t0 + r) * K + g * 8, &As[0][0] + (w * 16 + i * 64) * 32 + lane * 8);
    }
    {
        int g = sg4 ^ ((srb >> 1) & 3);
        glds16(B + (size_t)(n0 + srb) * K + g * 8, &Bs[0][0] + w * 512 + lane * 8);
    }
    __syncthreads();

    for (int kt = 0; kt < nk; ++kt) {
        if (kt + 1 < nk) {
            int k0 = (kt + 1) * 32, bi = (kt + 1) & 1;
            #pragma unroll
            for (int i = 0; i < 4; ++i) {
                int r = sra + i * 64;
                int g = sg4 ^ ((r >> 1) & 3);
                glds16(A + (size_t)(t0 + r) * K + k0 + g * 8, &As[bi][0] + (w * 16 + i * 64) * 32 + lane * 8);
            }
            int g = sg4 ^ ((srb >> 1) & 3);
            glds16(B + (size_t)(n0 + srb) * K + k0 + g * 8, &Bs[bi][0] + w * 512 + lane * 8);
        }
        const u16* as = &As[kt & 1][0];
        const u16* bs = &Bs[kt & 1][0];
        bf16x8 af[4], bfr[4];
        #pragma unroll
        for (int mi = 0; mi < 4; ++mi) af[mi]  = *(const bf16x8*)(as + aoff[mi]);
        #pragma unroll
        for (int ni = 0; ni < 4; ++ni) bfr[ni] = *(const bf16x8*)(bs + boff[ni]);
        if (!vblk) {
            #pragma unroll
            for (int mi = 0; mi < 4; ++mi)
                #pragma unroll
                for (int ni = 0; ni < 4; ++ni)
                    acc[mi][ni] = __builtin_amdgcn_mfma_f32_16x16x32_bf16(af[mi], bfr[ni], acc[mi][ni], 0, 0, 0);
        } else {
            #pragma unroll
            for (int mi = 0; mi < 4; ++mi)
                #pragma unroll
                for (int ni = 0; ni < 4; ++ni)
                    acc[mi][ni] = __builtin_amdgcn_mfma_f32_16x16x32_bf16(bfr[ni], af[mi], acc[mi][ni], 0, 0, 0);
        }
        __syncthreads();
    }

    if (vblk) {
        // V: acc = D[d = ni*16+quad*4+r][s = w*64+mi*16+l16], store bf16 to Vt[d][s]
        const int kv = bx - 20;
        u16* vbase = Vt + (size_t)(b * 4 + kv) * 64 * 2048;
        const int si = (t0 + w * 64 + l16) & 2047;
        #pragma unroll
        for (int mi = 0; mi < 4; ++mi)
            #pragma unroll
            for (int ni = 0; ni < 4; ++ni) {
                int d = ni * 16 + quad * 4;
                #pragma unroll
                for (int r = 0; r < 4; ++r)
                    vbase[(size_t)(d + r) * 2048 + si + mi * 16] = f2bf(acc[mi][ni][r]);
            }
    } else {
        // Q/K: RMSNorm + RoPE (+gain*0.125*log2e for Q)
        const bool isQ = bx < 16;
        const float sc = 0.18033688011112042f;
        const float g = isQ ? gain[bx] * sc : 1.0f;
        u16* base = isQ ? (Qb + (size_t)(b * 16 + bx) * 2048 * 64)
                        : (Kb + (size_t)(b * 4 + (bx - 16)) * 2048 * 64);
        const float eps = 1.1920929e-7f;
        const float invf0 = (float)(1.0 / pow(10000.0, (double)l16 / 32.0));
        const float invf1 = (float)(1.0 / pow(10000.0, (double)(l16 + 16) / 32.0));
        #pragma unroll
        for (int mi = 0; mi < 4; ++mi) {
            #pragma unroll
            for (int r = 0; r < 4; ++r) {
                float v0 = acc[mi][0][r], v1 = acc[mi][1][r];
                float v2 = acc[mi][2][r], v3 = acc[mi][3][r];
                float ssq = (v0 * v0 + v1 * v1) + (v2 * v2 + v3 * v3);
                #pragma unroll
                for (int m = 1; m < 16; m <<= 1) ssq += __shfl_xor(ssq, m);
                float rn = 1.0f / sqrtf(ssq * (1.0f / 64.0f) + eps);
                int si = (t0 + w * 64 + mi * 16 + quad * 4 + r) & 2047;
                float a0 = (float)si * invf0, a1 = (float)si * invf1;
                float c0 = __cosf(a0), s0 = __sinf(a0);
                float c1 = __cosf(a1), s1 = __sinf(a1);
                float x1a = v0 * rn, x2a = v2 * rn;
                float x1b = v1 * rn, x2b = v3 * rn;
                u16* row = base + (size_t)si * 64;
                row[l16]      = f2bf((x1a * c0 + x2a * s0) * g);
                row[l16 + 32] = f2bf((x2a * c0 - x1a * s0) * g);
                row[l16 + 16] = f2bf((x1b * c1 + x2b * s1) * g);
                row[l16 + 48] = f2bf((x2b * c1 - x1b * s1) * g);
            }
        }
    }
}

// ============================================================================
// 3. GEMM (proj): C[M,N] fp32 = A[M,K]bf16 @ B[N,K]^T. 128M x 64N, dbuf,
//    one barrier/iter (R8 structure).
// ============================================================================
__global__ __launch_bounds__(256) void gemm_bt(
    const u16* __restrict__ A, const u16* __restrict__ B,
    float* __restrict__ C, int M, int N, int K) {
    __shared__ u16 As[2][128 * 32];
    __shared__ u16 Bs[2][64 * 32];
    const int tid = threadIdx.x;
    const int lane = tid & 63, w = tid >> 6;
    const int quad = lane >> 4, l16 = lane & 15;
    const int m0 = blockIdx.y * 128, n0 = blockIdx.x * 64;
    const int wm = (w >> 1) * 64, wn = (w & 1) * 32;

    const int sra = w * 16 + (lane >> 2);
    const int srb = tid >> 2;
    const int sg4 = lane & 3;

    f32x4 acc[4][2];
    f32x4 zero = {0.f, 0.f, 0.f, 0.f};
    #pragma unroll
    for (int i = 0; i < 4; ++i) { acc[i][0] = zero; acc[i][1] = zero; }

    int aoff[4], boff[2];
    #pragma unroll
    for (int mi = 0; mi < 4; ++mi) {
        int r = wm + mi * 16 + l16;
        aoff[mi] = r * 32 + (quad ^ ((r >> 1) & 3)) * 8;
    }
    #pragma unroll
    for (int ni = 0; ni < 2; ++ni) {
        int r = wn + ni * 16 + l16;
        boff[ni] = r * 32 + (quad ^ ((r >> 1) & 3)) * 8;
    }

    const int nk = K >> 5;
    #pragma unroll
    for (int i = 0; i < 2; ++i) {
        int r = sra + i * 64;
        int g = sg4 ^ ((r >> 1) & 3);
        glds16(A + (size_t)(m0 + r) * K + g * 8, &As[0][0] + (w * 16 + i * 64) * 32 + lane * 8);
    }
    {
        int g = sg4 ^ ((srb >> 1) & 3);
        glds16(B + (size_t)(n0 + srb) * K + g * 8, &Bs[0][0] + w * 512 + lane * 8);
    }
    __syncthreads();

    for (int kt = 0; kt < nk; ++kt) {
        if (kt + 1 < nk) {
            int k0 = (kt + 1) * 32, bi = (kt + 1) & 1;
            #pragma unroll
            for (int i = 0; i < 2; ++i) {
                int r = sra + i * 64;
                int g = sg4 ^ ((r >> 1) & 3);
                glds16(A + (size_t)(m0 + r) * K + k0 + g * 8, &As[bi][0] + (w * 16 + i * 64) * 32 + lane * 8);
            }
            int g = sg4 ^ ((srb >> 1) & 3);
            glds16(B + (size_t)(n0 + srb) * K + k0 + g * 8, &Bs[bi][0] + w * 512 + lane * 8);
        }
        const u16* as = &As[kt & 1][0];
        const u16* bs = &Bs[kt & 1][0];
        bf16x8 af[4], bfr[2];
        #pragma unroll
        for (int mi = 0; mi < 4; ++mi) af[mi]  = *(const bf16x8*)(as + aoff[mi]);
        #pragma unroll
        for (int ni = 0; ni < 2; ++ni) bfr[ni] = *(const bf16x8*)(bs + boff[ni]);
        #pragma unroll
        for (int mi = 0; mi < 4; ++mi)
            #pragma unroll
            for (int ni = 0; ni < 2; ++ni)
                acc[mi][ni] = __builtin_amdgcn_mfma_f32_16x16x32_bf16(af[mi], bfr[ni], acc[mi][ni], 0, 0, 0);
        __syncthreads();
    }
    #pragma unroll
    for (int mi = 0; mi < 4; ++mi)
        #pragma unroll
        for (int ni = 0; ni < 2; ++ni) {
            int rg = m0 + wm + mi * 16 + quad * 4;
            int cg = n0 + wn + ni * 16 + l16;
            float* cp = C + (size_t)rg * N + cg;
            #pragma unroll
            for (int r = 0; r < 4; ++r) cp[(size_t)r * N] = acc[mi][ni][r];
        }
}

// ============================================================================
// 4. Flash attention, static per-head softmax max (ratio-exact). 512 thr,
//    8 waves x one 16-row band, Q-tile 128, split-K chunks (grid 32x24).
// ============================================================================
__global__ __launch_bounds__(512, 4) void attn(
    const u16* __restrict__ Qb, const u16* __restrict__ Kb,
    const u16* __restrict__ Vt, const float* __restrict__ gain,
    float* __restrict__ y, float* __restrict__ Opart, float* __restrict__ ml) {
    __shared__ u16 Ks[2][64 * 64];
    __shared__ u16 Vsh[2][64 * 64];
    const int hb = blockIdx.x;
    const int h = hb & 15, b = hb >> 4, kvh = h >> 2;
    const int yid = blockIdx.y;
    int bq, c0; bool partial;
    if (yid < 16) { bq = 15 - (yid >> 1); c0 = (yid & 1) * 16; partial = true; }
    else          { bq = 23 - yid;        c0 = 0;              partial = false; }
    const int nj = partial ? (c0 ? (2 * bq - 14) : 16) : (2 * bq + 2);
    const int q0 = bq * 128;
    const int tid = threadIdx.x, lane = tid & 63, w = tid >> 6;
    const int quad = lane >> 4, l16 = lane & 15;
    const float nM = -(12.0f * fabsf(gain[h]) + 1.0f);

    const u16* Qg = Qb + ((size_t)(b * 16 + h) * 2048 + q0) * 64;
    const u16* Kg = Kb + (size_t)(b * 4 + kvh) * 2048 * 64;
    const u16* Vg = Vt + (size_t)(b * 4 + kvh) * 64 * 2048;

    const bf16x8 qa0 = *(const bf16x8*)(Qg + (size_t)(w * 16 + l16) * 64 + quad * 8);
    const bf16x8 qa1 = *(const bf16x8*)(Qg + (size_t)(w * 16 + l16) * 64 + 32 + quad * 8);

    const int sr = tid >> 3;
    const int sg = (tid & 7) ^ (sr & 7);
    u16* kd[2] = {&Ks[0][0] + tid * 8, &Ks[1][0] + tid * 8};
    u16* vd[2] = {&Vsh[0][0] + tid * 8, &Vsh[1][0] + tid * 8};

    {
        int c = (c0 + nj - 1) * 64;
        glds16(Kg + (size_t)(c + sr) * 64 + sg * 8, kd[(nj - 1) & 1]);
        glds16(Vg + (size_t)sr * 2048 + c + sg * 8, vd[(nj - 1) & 1]);
    }
    __syncthreads();

    f32x4 o[4];
    f32x4 zero = {0.f, 0.f, 0.f, 0.f};
    #pragma unroll
    for (int t = 0; t < 4; ++t) o[t] = zero;
    float l = 0.f;

    for (int jj = nj - 1; jj >= 0; --jj) {
        if (jj > 0) {
            int c = (c0 + jj - 1) * 64;
            glds16(Kg + (size_t)(c + sr) * 64 + sg * 8, kd[(jj - 1) & 1]);
            glds16(Vg + (size_t)sr * 2048 + c + sg * 8, vd[(jj - 1) & 1]);
        }
        const u16* Kt = (jj & 1) ? &Ks[1][0] : &Ks[0][0];
        const u16* Vl = (jj & 1) ? &Vsh[1][0] : &Vsh[0][0];
        const int d = 8 * bq + w - 4 * (c0 + jj);
        if (d >= 0) {
            const int tmax = d < 3 ? d : 3;
            f32x4 st[4];
            #pragma unroll
            for (int t = 0; t < 4; ++t) {
                if (t <= tmax) {
                    int rk = t * 16 + l16;
                    bf16x8 kb0 = *(const bf16x8*)(Kt + rk * 64 + ((quad ^ (rk & 7)) * 8));
                    bf16x8 kb1 = *(const bf16x8*)(Kt + rk * 64 + (((quad + 4) ^ (rk & 7)) * 8));
                    f32x4 s = __builtin_amdgcn_mfma_f32_16x16x32_bf16(kb0, qa0, zero, 0, 0, 0);
                    s = __builtin_amdgcn_mfma_f32_16x16x32_bf16(kb1, qa1, s, 0, 0, 0);
                    if (t == d) {
                        #pragma unroll
                        for (int r = 0; r < 4; ++r)
                            if (quad * 4 + r > l16) s[r] = -1e30f;
                    }
                    st[t] = s;
                }
            }
            float rs = 0.f;
            s16x4 pf[4];
            #pragma unroll
            for (int t = 0; t < 4; ++t) {
                if (t <= tmax) {
                    float p0 = __builtin_amdgcn_exp2f(st[t][0] + nM);
                    float p1 = __builtin_amdgcn_exp2f(st[t][1] + nM);
                    float p2 = __builtin_amdgcn_exp2f(st[t][2] + nM);
                    float p3 = __builtin_amdgcn_exp2f(st[t][3] + nM);
                    rs += (p0 + p1) + (p2 + p3);
                    pf[t] = pack_bf4(p0, p1, p2, p3);
                }
            }
            rs += __shfl_xor(rs, 16);
            rs += __shfl_xor(rs, 32);
            l += rs;
            #pragma unroll
            for (int dt = 0; dt < 4; ++dt) {
                int rv = dt * 16 + l16;
                #pragma unroll
                for (int kt = 0; kt < 4; ++kt) {
                    if (kt <= tmax) {
                        int gv = 2 * kt + (quad >> 1);
                        s16x4 va = *(const s16x4*)(Vl + rv * 64 + ((gv ^ (rv & 7)) * 8) + (quad & 1) * 4);
                        o[dt] = MFMA16(va, pf[kt], o[dt]);
                    }
                }
            }
        }
        __syncthreads();
    }

    const int q = w * 16 + l16;
    if (!partial) {
        const float inv = 1.0f / l;
        const size_t row = (size_t)b * 2048 + q0 + q;
        #pragma unroll
        for (int dt = 0; dt < 4; ++dt) {
            f32x4 a = o[dt] * inv;
            *(f32x4*)(&y[row * 1024 + h * 64 + dt * 16 + quad * 4]) = a;
        }
    } else {
        const int slot = (hb * 8 + (bq - 8)) * 2 + (c0 ? 1 : 0);
        float* Op = Opart + (size_t)slot * 8192;
        #pragma unroll
        for (int dt = 0; dt < 4; ++dt)
            *(f32x4*)(Op + q * 64 + dt * 16 + quad * 4) = o[dt];
        if (quad == 0) ml[slot * 128 + q] = l;
    }
}

// ============================================================================
// 5. rmsnorm_merge: rows s<1024 read y; rows s>=1024 combine split-K partials
//    ((x0+x1)/(l0+l1), shared static M). Output bf16.
// ============================================================================
__global__ __launch_bounds__(256) void rmsnorm_merge(
    const float* __restrict__ y, const float* __restrict__ Opart,
    const float* __restrict__ ml, u16* __restrict__ yb) {
    __shared__ float red[4];
    const int row = blockIdx.x, tid = threadIdx.x;
    const int b = row >> 11, s = row & 2047;
    float4 v;
    if (s < 1024) {
        v = *(const float4*)(y + (size_t)row * 1024 + tid * 4);
    } else {
        const int bq = s >> 7, q = s & 127;
        const int e = tid * 4, h = e >> 6, dh = e & 63;
        const int slot = ((b * 16 + h) * 8 + (bq - 8)) * 2;
        float l0 = ml[slot * 128 + q];
        float l1 = ml[(slot + 1) * 128 + q];
        float inv = 1.0f / (l0 + l1);
        const float* P0 = Opart + (size_t)slot * 8192 + q * 64 + dh;
        f32x4 x0 = *(const f32x4*)P0;
        f32x4 x1 = *(const f32x4*)(P0 + 8192);
        f32x4 r = (x0 + x1) * inv;
        v.x = r[0]; v.y = r[1]; v.z = r[2]; v.w = r[3];
    }
    float ss = v.x * v.x + v.y * v.y + v.z * v.z + v.w * v.w;
    #pragma unroll
    for (int m = 1; m < 64; m <<= 1) ss += __shfl_xor(ss, m);
    if ((tid & 63) == 0) red[tid >> 6] = ss;
    __syncthreads();
    float tot = red[0] + red[1] + red[2] + red[3];
    float rn = 1.0f / sqrtf(tot * (1.0f / 1024.0f) + 1.1920929e-7f);
    u16 o[4] = {f2bf(v.x * rn), f2bf(v.y * rn), f2bf(v.z * rn), f2bf(v.w * rn)};
    *(uint2*)(yb + (size_t)row * 1024 + tid * 4) = *(const uint2*)o;
}

// ============================================================================
// launch — workspace (peak 48.50 MB):
//   [0,      2.10M)  wproj_b  (prep -> gemm2)
//   [2.10M, 10.49M)  xb (prep -> gemm_qkv); then y@2.10M..18.87M (attn->rms)
//   [10.49M,13.63M)  wqkv_b (prep -> gemm_qkv)  [covered by y later]
//   [18.87M,27.26M)  Qb (gemm_qkv -> attn); then yb (rms -> gemm2)
//   [27.26M,29.36M)  Kb   [29.36M,31.46M) Vt
//   [31.46M,48.23M)  Opart (attn -> rms)   [48.23M,48.50M) ml
// ============================================================================
extern "C" void kernel_launch(void* const* d_in, const int* in_sizes, int n_in,
                              void* d_out, int out_size, void* d_ws, size_t ws_size,
                              hipStream_t stream) {
    const float* x      = (const float*)d_in[0];
    const float* w_qkv  = (const float*)d_in[1];
    const float* w_proj = (const float*)d_in[2];
    const float* q_gain = (const float*)d_in[3];
    float* out = (float*)d_out;
    char* ws = (char*)d_ws;

    u16*   wproj_b = (u16*)(ws);
    u16*   xb      = (u16*)(ws + 2097152);
    float* y       = (float*)(ws + 2097152);
    u16*   wqkv_b  = (u16*)(ws + 10485760);
    u16*   Qb      = (u16*)(ws + 18874368);
    u16*   yb      = (u16*)(ws + 18874368);
    u16*   Kb      = (u16*)(ws + 27262976);
    u16*   Vt      = (u16*)(ws + 29360128);
    float* Opart   = (float*)(ws + 31457280);
    float* mlb     = (float*)(ws + 48234496);

    prep<<<3328, 256, 0, stream>>>(w_qkv, w_proj, x, wqkv_b, wproj_b, xb);
    gemm_qkv<<<dim3(24, 16), 256, 0, stream>>>(xb, wqkv_b, q_gain, Qb, Kb, Vt);
    attn<<<dim3(32, 24), 512, 0, stream>>>(Qb, Kb, Vt, q_gain, y, Opart, mlb);
    rmsnorm_merge<<<4096, 256, 0, stream>>>(y, Opart, mlb, yb);
    gemm_bt<<<dim3(16, 32), 256, 0, stream>>>(yb, wproj_b, out, 4096, 1024, 1024);
}